// Round 7
// baseline (86.526 us; speedup 1.0000x reference)
//
#include <hip/hip_runtime.h>

// KAN conv as densified GEMM: out[px,f] = sum_k Basis[px,k] * W[k,f]
//   px = (b,p,q) 8192, f = 64, K = 16 chunks x 640:
//   chunk kl in [0,576): spline (cl*144 + ij*16 + g), taps (1-fr)@idx, fr@idx+1
//   chunk kl in [576,640): silu at cl*16 + ij (ij<9), rest zero-pad (W rows 0)
// W pre-swizzled to MFMA 16x16x32 f16 B-fragment order. Basis in LDS with
// self-clearing scatter, XOR bank-swizzle phys = row*1280 + (intra^((row&7)<<4)).
// THIS REVISION: M-tile 32 -> 64 px (two image rows).
//   B-L2 traffic = (#M-tiles) x 1.31 MB (K-split-invariant, r5 lesson), so
//   M=64 halves it: 328 -> 168 MB (~4.9 us floor). Basis = 64x1280 B = 80 KiB
//   -> exactly 2 blocks/CU (160 KiB pool). Grid 512 = 128 M-tiles x 4-way
//   K-split (4 chunks each). Per kstep each wave now reads 4 A-frags (rows
//   m, m+16, m+32, m+48 -- same XOR mask, 16|32|48 = 0 mod 8) and does 16
//   MFMA; longer phases amortize the 2 barriers/chunk better, and per-CU
//   barrier count halves. Epilogue atomicAdds into out (4 contenders).
//   2 dispatches, no partials.

typedef _Float16 v8h __attribute__((ext_vector_type(8)));
typedef float    v4f __attribute__((ext_vector_type(4)));

#define NSLOT8  81920             // v8h slot-groups in wsw (655360 f16 / 8)
#define NOUT4   131072            // v4f groups in out (8192*64 f32 / 4)

// Wsw slot ((ks*4+nt)*64+lane)*8+j = W[k=ks*32+(lane>>4)*8+j][f=nt*16+(lane&15)]
__global__ __launch_bounds__(256) void prep_wsw(const float* __restrict__ cp,
                                                const float* __restrict__ w1,
                                                const float* __restrict__ w2,
                                                _Float16* __restrict__ wsw,
                                                float* __restrict__ out) {
    int tid = blockIdx.x * 256 + threadIdx.x;    // 0..131071 (512 blocks)
    if (tid < NSLOT8) {
        int lane = tid & 63;
        int rest = tid >> 6;
        int nt   = rest & 3;
        int ks   = rest >> 2;
        int kb   = ks * 32 + ((lane >> 4) << 3); // 8-aligned k base
        int f    = (nt << 4) + (lane & 15);
        int chunk = kb / 640;
        int klb   = kb - chunk * 640;
        v8h o;
        if (klb < 576) {
            int c  = (chunk << 2) + klb / 144;
            int rb = klb % 144;                  // 8-aligned, ij constant
            int ij = rb >> 4;
            float w = w1[f * 576 + c * 9 + ij];
            const v4f* cpp = (const v4f*)(cp + (size_t)f * 9216 + c * 144 + rb);
            v4f lo = cpp[0], hi = cpp[1];
#pragma unroll
            for (int j = 0; j < 4; ++j) {
                o[j]     = (_Float16)(w * lo[j]);
                o[j + 4] = (_Float16)(w * hi[j]);
            }
        } else {
            int i2 = klb - 576;                  // 8-aligned
            int c  = (chunk << 2) + (i2 >> 4);
            if ((i2 & 15) == 0) {                // ij = 0..7, all valid
#pragma unroll
                for (int j = 0; j < 8; ++j)
                    o[j] = (_Float16)w2[f * 576 + c * 9 + j];
            } else {                             // ij = 8..15, only ij==8 valid
#pragma unroll
                for (int j = 0; j < 8; ++j) o[j] = (_Float16)0.f;
                o[0] = (_Float16)w2[f * 576 + c * 9 + 8];
            }
        }
        ((v8h*)wsw)[tid] = o;
    }
    if (tid < NOUT4) ((v4f*)out)[tid] = (v4f){0.f, 0.f, 0.f, 0.f};
}

// grid 512: kh = blk>>7 (chunks kh*4..+4), mt = blk&127: b = mt>>4,
// row-pair p0 = (mt&15)*2 -> px tile = rows {p0,p0+1}, 64 px. 4 waves split
// each chunk's 20 ksteps (5 each); each wave holds the full 64x64 fp32
// accumulator (acc[4][4]); LDS reduce; atomicAdd into out (4 contenders).
// Basis: row q (0..63), 640 f16 = 1280 B/row; phys byte =
// q*1280 + (intra ^ ((q&7)<<4)). 81920 B -> 2 blocks/CU (LDS-exact).
__global__ __launch_bounds__(256, 2) void kan_mfma(const float* __restrict__ x,
                                                   const _Float16* __restrict__ wsw,
                                                   float* __restrict__ out) {
    __shared__ __align__(16) char smem[81920];
    float* red = (float*)smem;             // [4][64][65] f32 reduce (66560 B)

    int blk = blockIdx.x;
    int kh  = blk >> 7;                    // 0..3
    int mt  = blk & 127;
    int b = mt >> 4, p0 = (mt & 15) << 1;
    int t = threadIdx.x, wv = t >> 6, lane = t & 63;
    int m = lane & 15, kq = lane >> 4;

    int ch0 = kh * 4, ch1 = ch0 + 4;
    const float* xb = x + (size_t)b * 65536;

    // ---- scatter geometry: 576 (q,ij) items, 144 per wave ----
    // it0/it1: e = wv*144 + it*64 + lane (all lanes); it2: +128+lane (lane<16)
    int xoff[3], sbase[3], smask[3], ijb[3];
    bool act[3];
#pragma unroll
    for (int it = 0; it < 3; ++it) {
        bool a = (it < 2) || (lane < 16);
        int e  = a ? (wv * 144 + it * 64 + lane) : 0;
        int q  = e / 9;
        int ij = e - q * 9;
        int di = ij / 3;
        int dj = ij - di * 3;
        int row = p0 + (q >> 5) + di - 1;
        int col = (q & 31) + dj - 1;
        bool ok = ((unsigned)row < 32u) && ((unsigned)col < 32u) && a;
        act[it]   = a;
        xoff[it]  = ok ? (row * 32 + col) * 64 : -1;   // sign = halo flag
        sbase[it] = q * 1280;                          // row byte base
        smask[it] = (q & 7) << 4;                      // XOR swizzle mask
        ijb[it]   = ij * 32;                           // ij*16 slots * 2 B
    }

    v4f z4 = (v4f){0.f, 0.f, 0.f, 0.f};
    v4f acc[4][4];
#pragma unroll
    for (int i = 0; i < 4; ++i)
#pragma unroll
        for (int n = 0; n < 4; ++n) acc[i][n] = z4;

    // zero basis (81920 B = 5120 v4f)
    for (int i4 = t; i4 < 5120; i4 += 256) ((v4f*)smem)[i4] = z4;

    // prologue x prefetch for first chunk
    v4f vbuf[3];
#pragma unroll
    for (int it = 0; it < 3; ++it)
        vbuf[it] = (xoff[it] >= 0) ? *(const v4f*)(xb + xoff[it] + ch0 * 4) : z4;
    unsigned pk[3] = {0u, 0u, 0u};

    __syncthreads();   // zeros visible

    for (int gch = ch0; gch < ch1; ++gch) {
        // ---- scatter: 4 channels per item; swizzled 2-byte writes.
        // halo items (xoff<0, v=0) still scatter: taps (0.5,0.5)@7 match the
        // reference (padding taps DO contribute); silu(0)=0.
#pragma unroll
        for (int it = 0; it < 3; ++it) {
            if (act[it]) {
                v4f xv = vbuf[it];
                char* rowp = smem + sbase[it];
                int mask = smask[it];
                int jb   = ijb[it];
                unsigned pp = pk[it], np = 0;
#pragma unroll
                for (int cl = 0; cl < 4; ++cl) {
                    float v  = xv[cl];
                    float xc = fminf(fmaxf(v, -1.f), 1.f);
                    float tt = (xc + 1.f) * 7.5f;
                    int idx  = (int)tt;
                    if (idx > 14) idx = 14;
                    float fr = tt - (float)idx;
                    float sv = v * __builtin_amdgcn_rcpf(1.f + __expf(-v));
                    int sb0 = cl * 288 + jb;           // spline block byte base
                    if (gch > ch0) {                   // self-clear prev taps
                        int pb = sb0 + (int)((pp >> (cl * 8)) & 255) * 2;
                        *(_Float16*)(rowp + (pb ^ mask))       = (_Float16)0.f;
                        *(_Float16*)(rowp + ((pb + 2) ^ mask)) = (_Float16)0.f;
                    }
                    int wb = sb0 + idx * 2;
                    *(_Float16*)(rowp + (wb ^ mask))       = (_Float16)(1.f - fr);
                    *(_Float16*)(rowp + ((wb + 2) ^ mask)) = (_Float16)fr;
                    *(_Float16*)(rowp + ((1152 + cl * 32 + (jb >> 4)) ^ mask))
                        = (_Float16)sv;                // silu slot (overwrite)
                    np |= (unsigned)idx << (cl * 8);
                }
                pk[it] = np;
            }
        }
        __syncthreads();
        // prefetch next chunk's x (drains at the next barrier, under MFMA)
        if (gch + 1 < ch1) {
#pragma unroll
            for (int it = 0; it < 3; ++it)
                vbuf[it] = (xoff[it] >= 0)
                         ? *(const v4f*)(xb + xoff[it] + (gch + 1) * 4) : z4;
        }
        // ---- MFMA: 20 ksteps, this wave takes 5; 4 A-frags, 16 MFMA each ----
        const v8h* bp = (const v8h*)wsw + ((size_t)gch * 20 + wv * 5) * 256 + lane;
        int mbase = m * 1280;
        int mm    = (m & 7) << 4;
#pragma unroll
        for (int s = 0; s < 5; ++s) {
            int kx = (((wv * 5 + s) * 64) + (kq * 16)) ^ mm;
            v8h a0 = *(const v8h*)(smem + mbase + kx);
            v8h a1 = *(const v8h*)(smem + mbase + 20480 + kx);   // row m+16
            v8h a2 = *(const v8h*)(smem + mbase + 40960 + kx);   // row m+32
            v8h a3 = *(const v8h*)(smem + mbase + 61440 + kx);   // row m+48
            v8h b0 = bp[s * 256];
            v8h b1 = bp[s * 256 + 64];
            v8h b2 = bp[s * 256 + 128];
            v8h b3 = bp[s * 256 + 192];
            acc[0][0] = __builtin_amdgcn_mfma_f32_16x16x32_f16(a0, b0, acc[0][0], 0, 0, 0);
            acc[0][1] = __builtin_amdgcn_mfma_f32_16x16x32_f16(a0, b1, acc[0][1], 0, 0, 0);
            acc[0][2] = __builtin_amdgcn_mfma_f32_16x16x32_f16(a0, b2, acc[0][2], 0, 0, 0);
            acc[0][3] = __builtin_amdgcn_mfma_f32_16x16x32_f16(a0, b3, acc[0][3], 0, 0, 0);
            acc[1][0] = __builtin_amdgcn_mfma_f32_16x16x32_f16(a1, b0, acc[1][0], 0, 0, 0);
            acc[1][1] = __builtin_amdgcn_mfma_f32_16x16x32_f16(a1, b1, acc[1][1], 0, 0, 0);
            acc[1][2] = __builtin_amdgcn_mfma_f32_16x16x32_f16(a1, b2, acc[1][2], 0, 0, 0);
            acc[1][3] = __builtin_amdgcn_mfma_f32_16x16x32_f16(a1, b3, acc[1][3], 0, 0, 0);
            acc[2][0] = __builtin_amdgcn_mfma_f32_16x16x32_f16(a2, b0, acc[2][0], 0, 0, 0);
            acc[2][1] = __builtin_amdgcn_mfma_f32_16x16x32_f16(a2, b1, acc[2][1], 0, 0, 0);
            acc[2][2] = __builtin_amdgcn_mfma_f32_16x16x32_f16(a2, b2, acc[2][2], 0, 0, 0);
            acc[2][3] = __builtin_amdgcn_mfma_f32_16x16x32_f16(a2, b3, acc[2][3], 0, 0, 0);
            acc[3][0] = __builtin_amdgcn_mfma_f32_16x16x32_f16(a3, b0, acc[3][0], 0, 0, 0);
            acc[3][1] = __builtin_amdgcn_mfma_f32_16x16x32_f16(a3, b1, acc[3][1], 0, 0, 0);
            acc[3][2] = __builtin_amdgcn_mfma_f32_16x16x32_f16(a3, b2, acc[3][2], 0, 0, 0);
            acc[3][3] = __builtin_amdgcn_mfma_f32_16x16x32_f16(a3, b3, acc[3][3], 0, 0, 0);
        }
        __syncthreads();
    }

    // ---- 4-wave LDS reduction, then coalesced atomicAdd into out ----
#pragma unroll
    for (int mtile = 0; mtile < 4; ++mtile)
#pragma unroll
        for (int nt = 0; nt < 4; ++nt)
#pragma unroll
            for (int r = 0; r < 4; ++r)
                red[wv * 4160 + (mtile * 16 + kq * 4 + r) * 65 + nt * 16 + m]
                    = acc[mtile][nt][r];
    __syncthreads();
    int f = t & 63, pxg = t >> 6;            // pxg in [0,4)
    float* op = out + ((size_t)(b * 32 + p0) * 32) * 64 + f;
#pragma unroll
    for (int i = 0; i < 16; ++i) {
        int px = pxg * 16 + i;
        float s = red[px * 65 + f] + red[4160 + px * 65 + f]
                + red[8320 + px * 65 + f] + red[12480 + px * 65 + f];
        atomicAdd(op + px * 64, s);
    }
}

extern "C" void kernel_launch(void* const* d_in, const int* in_sizes, int n_in,
                              void* d_out, int out_size, void* d_ws, size_t ws_size,
                              hipStream_t stream) {
    const float* x  = (const float*)d_in[0];
    const float* cp = (const float*)d_in[1];
    const float* w1 = (const float*)d_in[2];
    const float* w2 = (const float*)d_in[3];
    _Float16* wsw = (_Float16*)d_ws;                       // 1.31 MB
    float*    outp = (float*)d_out;

    prep_wsw<<<512, 256, 0, stream>>>(cp, w1, w2, wsw, outp);
    kan_mfma<<<512, 256, 0, stream>>>(x, wsw, outp);
}

// Round 8
// 82.152 us; speedup vs baseline: 1.0532x; 1.0532x over previous
//
#include <hip/hip_runtime.h>

// KAN conv as densified GEMM: out[px,f] = sum_k Basis[px,k] * W[k,f]
//   px = (b,p,q) 8192, f = 64, K = 16 chunks x 640:
//   chunk kl in [0,576): spline (cl*144 + ij*16 + g), taps (1-fr)@idx, fr@idx+1
//   chunk kl in [576,640): silu at cl*16 + ij (ij<9), rest zero-pad (W rows 0)
// W pre-swizzled to MFMA 16x16x32 f16 B-fragment order. Basis in LDS with
// self-clearing scatter, XOR bank-swizzle phys = row*1280 + (intra^((row&7)<<4)).
// THIS REVISION: r6 geometry (M=32, 4-chunk K-split, 40960 B basis, 4 blk/CU)
// with 512-THREAD blocks -> 32 waves/CU (was 16).
//   r5/r6/r7 together showed kan is STALL-bound: traffic changes lose to
//   occupancy changes. LDS pins blocks/CU at 4; the free axis is waves/block.
//   8 waves = (kstep-group wg 0-3) x (N-half nh 0-1); wave does 5 ksteps x
//   2 A-frags x 2 B-frags = 20 MFMA, acc[2][2] (16 VGPR). Each B-frag still
//   read once per block (traffic invariant 327 MB). __launch_bounds__(512,8)
//   caps VGPR at 64 for 4 blocks x 8 waves = 32 waves/CU.
//   Epilogue: [4][32][65] LDS reduce over wg, atomicAdd into out.

typedef _Float16 v8h __attribute__((ext_vector_type(8)));
typedef float    v4f __attribute__((ext_vector_type(4)));

#define NSLOT8  81920             // v8h slot-groups in wsw (655360 f16 / 8)
#define NOUT4   131072            // v4f groups in out (8192*64 f32 / 4)

// Wsw slot ((ks*4+nt)*64+lane)*8+j = W[k=ks*32+(lane>>4)*8+j][f=nt*16+(lane&15)]
__global__ __launch_bounds__(256) void prep_wsw(const float* __restrict__ cp,
                                                const float* __restrict__ w1,
                                                const float* __restrict__ w2,
                                                _Float16* __restrict__ wsw,
                                                float* __restrict__ out) {
    int tid = blockIdx.x * 256 + threadIdx.x;    // 0..131071 (512 blocks)
    if (tid < NSLOT8) {
        int lane = tid & 63;
        int rest = tid >> 6;
        int nt   = rest & 3;
        int ks   = rest >> 2;
        int kb   = ks * 32 + ((lane >> 4) << 3); // 8-aligned k base
        int f    = (nt << 4) + (lane & 15);
        int chunk = kb / 640;
        int klb   = kb - chunk * 640;
        v8h o;
        if (klb < 576) {
            int c  = (chunk << 2) + klb / 144;
            int rb = klb % 144;                  // 8-aligned, ij constant
            int ij = rb >> 4;
            float w = w1[f * 576 + c * 9 + ij];
            const v4f* cpp = (const v4f*)(cp + (size_t)f * 9216 + c * 144 + rb);
            v4f lo = cpp[0], hi = cpp[1];
#pragma unroll
            for (int j = 0; j < 4; ++j) {
                o[j]     = (_Float16)(w * lo[j]);
                o[j + 4] = (_Float16)(w * hi[j]);
            }
        } else {
            int i2 = klb - 576;                  // 8-aligned
            int c  = (chunk << 2) + (i2 >> 4);
            if ((i2 & 15) == 0) {                // ij = 0..7, all valid
#pragma unroll
                for (int j = 0; j < 8; ++j)
                    o[j] = (_Float16)w2[f * 576 + c * 9 + j];
            } else {                             // ij = 8..15, only ij==8 valid
#pragma unroll
                for (int j = 0; j < 8; ++j) o[j] = (_Float16)0.f;
                o[0] = (_Float16)w2[f * 576 + c * 9 + 8];
            }
        }
        ((v8h*)wsw)[tid] = o;
    }
    if (tid < NOUT4) ((v4f*)out)[tid] = (v4f){0.f, 0.f, 0.f, 0.f};
}

// grid 1024 x 512 thr: kh = blk>>8 (chunks kh*4..+4), rowid = blk&255 = (b,p).
// WG = 32 px (one image row), 8 waves. Basis: row q (0..31), 640 f16 =
// 1280 B/row; phys byte = q*1280 + (intra ^ ((q&7)<<4)). 40960 B ->
// 4 blocks/CU (LDS-exact), 32 waves/CU at VGPR<=64.
__global__ __launch_bounds__(512, 8) void kan_mfma(const float* __restrict__ x,
                                                   const _Float16* __restrict__ wsw,
                                                   float* __restrict__ out) {
    __shared__ __align__(16) char smem[40960];
    float* red = (float*)smem;             // [4][32][65] f32 reduce (33280 B)

    int blk   = blockIdx.x;
    int kh    = blk >> 8;                  // 0..3
    int rowid = blk & 255;
    int b = rowid >> 5, p = rowid & 31;
    int t = threadIdx.x, wv = t >> 6, lane = t & 63;
    int m = lane & 15, kq = lane >> 4;
    int wg = wv >> 1, nh = wv & 1;         // kstep-group, N-half

    int ch0 = kh * 4, ch1 = ch0 + 4;
    const float* xb = x + (size_t)b * 65536;

    // ---- scatter geometry: 288 (q,ij) items, one per thread (t<288) ----
    bool act = t < 288;
    int xoff, sbase, smask, ijb;
    {
        int e  = act ? t : 0;
        int q  = e / 9;
        int ij = e - q * 9;
        int di = ij / 3;
        int dj = ij - di * 3;
        int row = p + di - 1;
        int col = q + dj - 1;
        bool ok = ((unsigned)row < 32u) && ((unsigned)col < 32u) && act;
        xoff  = ok ? (row * 32 + col) * 64 : -1;   // sign = halo flag
        sbase = q * 1280;                          // row byte base
        smask = (q & 7) << 4;                      // XOR swizzle mask
        ijb   = ij * 32;                           // ij*16 slots * 2 B
    }

    v4f z4 = (v4f){0.f, 0.f, 0.f, 0.f};
    v4f acc[2][2];
#pragma unroll
    for (int i = 0; i < 2; ++i)
#pragma unroll
        for (int n = 0; n < 2; ++n) acc[i][n] = z4;

    // zero basis (40960 B = 2560 v4f)
    for (int i4 = t; i4 < 2560; i4 += 512) ((v4f*)smem)[i4] = z4;

    // prologue x prefetch for first chunk
    v4f vbuf = (xoff >= 0) ? *(const v4f*)(xb + xoff + ch0 * 4) : z4;
    unsigned pk = 0u;

    __syncthreads();   // zeros visible

    for (int gch = ch0; gch < ch1; ++gch) {
        // ---- scatter: 4 channels per item; swizzled 2-byte writes.
        // halo items (xoff<0, v=0) still scatter: taps (0.5,0.5)@7 match the
        // reference (padding taps DO contribute); silu(0)=0.
        if (act) {
            v4f xv = vbuf;
            char* rowp = smem + sbase;
            unsigned pp = pk, np = 0;
#pragma unroll
            for (int cl = 0; cl < 4; ++cl) {
                float v  = xv[cl];
                float xc = fminf(fmaxf(v, -1.f), 1.f);
                float tt = (xc + 1.f) * 7.5f;
                int idx  = (int)tt;
                if (idx > 14) idx = 14;
                float fr = tt - (float)idx;
                float sv = v * __builtin_amdgcn_rcpf(1.f + __expf(-v));
                int sb0 = cl * 288 + ijb;          // spline block byte base
                if (gch > ch0) {                   // self-clear prev taps
                    int pb = sb0 + (int)((pp >> (cl * 8)) & 255) * 2;
                    *(_Float16*)(rowp + (pb ^ smask))       = (_Float16)0.f;
                    *(_Float16*)(rowp + ((pb + 2) ^ smask)) = (_Float16)0.f;
                }
                int wb = sb0 + idx * 2;
                *(_Float16*)(rowp + (wb ^ smask))       = (_Float16)(1.f - fr);
                *(_Float16*)(rowp + ((wb + 2) ^ smask)) = (_Float16)fr;
                *(_Float16*)(rowp + ((1152 + cl * 32 + (ijb >> 4)) ^ smask))
                    = (_Float16)sv;                // silu slot (overwrite)
                np |= (unsigned)idx << (cl * 8);
            }
            pk = np;
        }
        __syncthreads();
        // prefetch next chunk's x (drains at the next barrier, under MFMA)
        if (gch + 1 < ch1)
            vbuf = (xoff >= 0) ? *(const v4f*)(xb + xoff + (gch + 1) * 4) : z4;
        // ---- MFMA: wave (wg,nh) does 5 ksteps x 2 A-frags x 2 B-frags ----
        const v8h* bp = (const v8h*)wsw
                      + ((size_t)gch * 20 + wg * 5) * 256 + nh * 128 + lane;
        int mbase = m * 1280;
        int mm    = (m & 7) << 4;
#pragma unroll
        for (int s = 0; s < 5; ++s) {
            int kx = (((wg * 5 + s) * 64) + (kq * 16)) ^ mm;
            v8h a0 = *(const v8h*)(smem + mbase + kx);
            v8h a1 = *(const v8h*)(smem + mbase + 20480 + kx);   // row m+16
            v8h b0 = bp[s * 256];
            v8h b1 = bp[s * 256 + 64];
            acc[0][0] = __builtin_amdgcn_mfma_f32_16x16x32_f16(a0, b0, acc[0][0], 0, 0, 0);
            acc[0][1] = __builtin_amdgcn_mfma_f32_16x16x32_f16(a0, b1, acc[0][1], 0, 0, 0);
            acc[1][0] = __builtin_amdgcn_mfma_f32_16x16x32_f16(a1, b0, acc[1][0], 0, 0, 0);
            acc[1][1] = __builtin_amdgcn_mfma_f32_16x16x32_f16(a1, b1, acc[1][1], 0, 0, 0);
        }
        __syncthreads();
    }

    // ---- reduce over wg (4 partials) in LDS, then atomicAdd into out ----
    // C/D: row(M) = kq*4 + reg, col(N) = m. acc[mt][ntl] covers
    // M-block mt*16, N-block (nh*2+ntl)*16.
#pragma unroll
    for (int mt = 0; mt < 2; ++mt)
#pragma unroll
        for (int ntl = 0; ntl < 2; ++ntl)
#pragma unroll
            for (int r = 0; r < 4; ++r)
                red[wg * 2080 + (mt * 16 + kq * 4 + r) * 65
                    + (nh * 2 + ntl) * 16 + m] = acc[mt][ntl][r];
    __syncthreads();
    int f = t & 63, pg = t >> 6;             // pg in [0,8)
    float* op = out + (size_t)rowid * 2048 + f;
#pragma unroll
    for (int i = 0; i < 4; ++i) {
        int px = pg * 4 + i;
        float s = red[px * 65 + f] + red[2080 + px * 65 + f]
                + red[4160 + px * 65 + f] + red[6240 + px * 65 + f];
        atomicAdd(op + px * 64, s);
    }
}

extern "C" void kernel_launch(void* const* d_in, const int* in_sizes, int n_in,
                              void* d_out, int out_size, void* d_ws, size_t ws_size,
                              hipStream_t stream) {
    const float* x  = (const float*)d_in[0];
    const float* cp = (const float*)d_in[1];
    const float* w1 = (const float*)d_in[2];
    const float* w2 = (const float*)d_in[3];
    _Float16* wsw = (_Float16*)d_ws;                       // 1.31 MB
    float*    outp = (float*)d_out;

    prep_wsw<<<512, 256, 0, stream>>>(cp, w1, w2, wsw, outp);
    kan_mfma<<<1024, 512, 0, stream>>>(x, wsw, outp);
}